// Round 1
// baseline (930.921 us; speedup 1.0000x reference)
//
#include <hip/hip_runtime.h>
#include <hip/hip_bf16.h>

// C = triu( triu(A) @ triu(B) ), N=4096, fp32.
// Triangularity: A[i,k]=0 for k<i, B[k,j]=0 for k>j  =>
// block (bi,bj) only needs k in [bi*BM, (bj+1)*BN). Blocks with bj<bi have an
// empty k-range and just write zeros (output must be fully written: poisoned).

#define NDIM 4096
#define BM 128
#define BN 128
#define BK 16
#define TM 8
#define TN 8

__global__ __launch_bounds__(256) void trimm_f32_kernel(
    const float* __restrict__ A, const float* __restrict__ B,
    float* __restrict__ C) {
    const int bi = blockIdx.x;  // row-block
    const int bj = blockIdx.y;  // col-block
    const int tid = threadIdx.x;
    const int tx = tid & 15;    // micro-tile col index
    const int ty = tid >> 4;    // micro-tile row index

    __shared__ float Ast[BK][BM + 4];  // k-major A tile (transposed on stage)
    __shared__ float Bs[BK][BN + 4];   // k-major B tile (natural layout)

    const int row0 = bi * BM;
    const int col0 = bj * BN;

    float acc[TM][TN];
#pragma unroll
    for (int i = 0; i < TM; ++i)
#pragma unroll
        for (int j = 0; j < TN; ++j) acc[i][j] = 0.f;

    const int kstart = row0;                  // triu(A): k >= row
    const int kend = min(NDIM, col0 + BN);    // triu(B): k <= col

    for (int kt = kstart; kt < kend; kt += BK) {
        // ---- stage A: 128 rows x 16 k, transpose into Ast[k][row] ----
#pragma unroll
        for (int r = 0; r < 2; ++r) {
            const int f = tid + 256 * r;      // 0..511 float4 chunks
            const int row = f >> 2;           // 0..127
            const int kq = (f & 3) * 4;       // 0,4,8,12
            const float4 v = *reinterpret_cast<const float4*>(
                &A[(size_t)(row0 + row) * NDIM + kt + kq]);
            Ast[kq + 0][row] = v.x;
            Ast[kq + 1][row] = v.y;
            Ast[kq + 2][row] = v.z;
            Ast[kq + 3][row] = v.w;
        }
        // ---- stage B: 16 k-rows x 128 cols, direct float4 ----
#pragma unroll
        for (int r = 0; r < 2; ++r) {
            const int f = tid + 256 * r;      // 0..511
            const int kr = f >> 5;            // 0..15
            const int cq = (f & 31) * 4;      // 0..124
            const float4 v = *reinterpret_cast<const float4*>(
                &B[(size_t)(kt + kr) * NDIM + col0 + cq]);
            *reinterpret_cast<float4*>(&Bs[kr][cq]) = v;
        }
        __syncthreads();

        // ---- 8x8 micro-tile FMA, float4 LDS fragment reads ----
#pragma unroll
        for (int kk = 0; kk < BK; ++kk) {
            float a[TM], b[TN];
            *reinterpret_cast<float4*>(&a[0]) =
                *reinterpret_cast<const float4*>(&Ast[kk][ty * TM]);
            *reinterpret_cast<float4*>(&a[4]) =
                *reinterpret_cast<const float4*>(&Ast[kk][ty * TM + 4]);
            *reinterpret_cast<float4*>(&b[0]) =
                *reinterpret_cast<const float4*>(&Bs[kk][tx * TN]);
            *reinterpret_cast<float4*>(&b[4]) =
                *reinterpret_cast<const float4*>(&Bs[kk][tx * TN + 4]);
#pragma unroll
            for (int i = 0; i < TM; ++i)
#pragma unroll
                for (int j = 0; j < TN; ++j)
                    acc[i][j] = fmaf(a[i], b[j], acc[i][j]);
        }
        __syncthreads();
    }

    // ---- epilogue: upper-triangular element mask (zeros below diagonal) ----
#pragma unroll
    for (int i = 0; i < TM; ++i) {
        const int row = row0 + ty * TM + i;
#pragma unroll
        for (int j = 0; j < TN; j += 4) {
            const int col = col0 + tx * TN + j;
            float4 v;
            v.x = (row <= col + 0) ? acc[i][j + 0] : 0.f;
            v.y = (row <= col + 1) ? acc[i][j + 1] : 0.f;
            v.z = (row <= col + 2) ? acc[i][j + 2] : 0.f;
            v.w = (row <= col + 3) ? acc[i][j + 3] : 0.f;
            *reinterpret_cast<float4*>(&C[(size_t)row * NDIM + col]) = v;
        }
    }
}

extern "C" void kernel_launch(void* const* d_in, const int* in_sizes, int n_in,
                              void* d_out, int out_size, void* d_ws,
                              size_t ws_size, hipStream_t stream) {
    const float* A = (const float*)d_in[0];
    const float* B = (const float*)d_in[1];
    float* C = (float*)d_out;
    dim3 grid(NDIM / BM, NDIM / BN);
    trimm_f32_kernel<<<grid, 256, 0, stream>>>(A, B, C);
}

// Round 3
// 138.740 us; speedup vs baseline: 6.7098x; 6.7098x over previous
//
#include <hip/hip_runtime.h>
#include <hip/hip_bf16.h>

// C = triu( triu(A) @ triu(B) ), N=4096, fp32 in/out.
// bf16 MFMA (16x16x32), fp32->bf16 RNE conversion during LDS staging.
// Block (bi,bj) k-range = [bi*BM, (bj+1)*BN). Lower-tri blocks zero-fill.
// 1D grid, upper-tri blocks enumerated longest-k-first for load balance.
// LDS tiles use stride-80B rows (64B data + 16B pad): row base banks walk
// 0,20,8,28,16,4,24,12 (period 8) -> b128 fragment reads are 2-way (free).

#define NDIM 4096
#define BM 128
#define BN 128
#define BK 32
#define NBLK (NDIM / BM)                  // 32
#define NUPPER ((NBLK * (NBLK + 1)) / 2)  // 528
#define NTOT (NBLK * NBLK)                // 1024
#define LSTR 80                           // LDS row stride in bytes

typedef __attribute__((ext_vector_type(8))) short short8;
typedef __attribute__((ext_vector_type(4))) float floatx4;

__device__ __forceinline__ int loff(int row, int kb) {
    return row * LSTR + kb;   // kb = byte offset within 64B of row data
}

// fp32 -> bf16 bits, round-to-nearest-even (unbiased; truncation would bias).
__device__ __forceinline__ unsigned f2bf(float f) {
    unsigned u = __builtin_bit_cast(unsigned, f);
    return (u + 0x7fffu + ((u >> 16) & 1u)) >> 16;
}

__global__ __launch_bounds__(256) void trimm_mfma_kernel(
    const float* __restrict__ A, const float* __restrict__ B,
    float* __restrict__ C) {
    const int tid = threadIdx.x;
    const int id = blockIdx.x;
    int bi, bj;

    if (id >= NUPPER) {
        // ---- lower-triangle block: zero-fill (d_out is poisoned) ----
        int r = id - NUPPER;
        int p = 1;
        while (r >= p) { r -= p; ++p; }
        bi = p;
        bj = r;
        const size_t base = (size_t)bi * BM * NDIM + (size_t)bj * BN;
        const float4 z = make_float4(0.f, 0.f, 0.f, 0.f);
#pragma unroll
        for (int t = 0; t < 16; ++t) {
            const int f = tid + 256 * t;      // 0..4095 float4 chunks
            const int rr = f >> 5;            // 32 float4 per 128-col row
            const int cc = (f & 31) * 4;
            *reinterpret_cast<float4*>(&C[base + (size_t)rr * NDIM + cc]) = z;
        }
        return;
    }

    {   // ---- decode upper-tri block, longest k-range first ----
        int r = id;
        int L = NBLK;                         // k-length in blocks
        while (r >= NBLK + 1 - L) { r -= NBLK + 1 - L; --L; }
        bi = r;
        bj = bi + L - 1;
    }

    const int row0 = bi * BM;
    const int col0 = bj * BN;

    __shared__ __align__(16) char lAs[BM * LSTR];  // 10 KB, [row][k] bf16
    __shared__ __align__(16) char lBs[BN * LSTR];  // 10 KB, [col][k] bf16 (B^T)

    floatx4 acc[4][4];
    const floatx4 fz = {0.f, 0.f, 0.f, 0.f};
#pragma unroll
    for (int m = 0; m < 4; ++m)
#pragma unroll
        for (int n = 0; n < 4; ++n) acc[m][n] = fz;

    const int wv = tid >> 6;
    const int wr = (wv >> 1) * 64;     // wave row offset in tile
    const int wc = (wv & 1) * 64;      // wave col offset in tile
    const int lane = tid & 63;
    const int fr = lane & 15;          // fragment row/col index
    const int kb = (lane >> 4) * 16;   // byte offset of 8-bf16 k-chunk

    // B staging: thread owns one column, 16 k values (coalesced across lanes)
    const int bn = tid & 127;
    const int bkh = (tid >> 7) * 16;

    const int kend = col0 + BN;        // triu(B): k <= col
    for (int kt = row0; kt < kend; kt += BK) {   // triu(A): k >= row
        __syncthreads();
        // ---- stage A: copy-through rows, fp32->bf16, b64 writes ----
#pragma unroll
        for (int j = 0; j < 4; ++j) {
            const int f = tid + 256 * j;       // 0..1023 float4 chunks
            const int rr = f >> 3;             // 8 float4 per 32-float row
            const int kq = (f & 7) * 4;        // float index in row
            const float4 v = *reinterpret_cast<const float4*>(
                &A[(size_t)(row0 + rr) * NDIM + kt + kq]);
            uint2 w;
            w.x = f2bf(v.x) | (f2bf(v.y) << 16);
            w.y = f2bf(v.z) | (f2bf(v.w) << 16);
            *reinterpret_cast<uint2*>(lAs + loff(rr, kq * 2)) = w;
        }
        // ---- stage B: transpose to [col][k], k-contiguous b128 writes ----
        {
            float t[16];
#pragma unroll
            for (int kk = 0; kk < 16; ++kk)
                t[kk] = B[(size_t)(kt + bkh + kk) * NDIM + col0 + bn];
            uint4 w0, w1;
            w0.x = f2bf(t[0]) | (f2bf(t[1]) << 16);
            w0.y = f2bf(t[2]) | (f2bf(t[3]) << 16);
            w0.z = f2bf(t[4]) | (f2bf(t[5]) << 16);
            w0.w = f2bf(t[6]) | (f2bf(t[7]) << 16);
            w1.x = f2bf(t[8]) | (f2bf(t[9]) << 16);
            w1.y = f2bf(t[10]) | (f2bf(t[11]) << 16);
            w1.z = f2bf(t[12]) | (f2bf(t[13]) << 16);
            w1.w = f2bf(t[14]) | (f2bf(t[15]) << 16);
            *reinterpret_cast<uint4*>(lBs + loff(bn, bkh * 2)) = w0;
            *reinterpret_cast<uint4*>(lBs + loff(bn, bkh * 2 + 16)) = w1;
        }
        __syncthreads();

        // ---- fragments + 16 MFMAs (full K=32 per MFMA) ----
        short8 af[4], bf[4];
#pragma unroll
        for (int m = 0; m < 4; ++m)
            af[m] = *reinterpret_cast<const short8*>(
                lAs + loff(wr + m * 16 + fr, kb));
#pragma unroll
        for (int n = 0; n < 4; ++n)
            bf[n] = *reinterpret_cast<const short8*>(
                lBs + loff(wc + n * 16 + fr, kb));
#pragma unroll
        for (int m = 0; m < 4; ++m)
#pragma unroll
            for (int n = 0; n < 4; ++n)
                acc[m][n] = __builtin_amdgcn_mfma_f32_16x16x32_bf16(
                    af[m], bf[n], acc[m][n], 0, 0, 0);
    }

    // ---- epilogue: C/D layout col=lane&15, row=(lane>>4)*4+reg ----
#pragma unroll
    for (int m = 0; m < 4; ++m) {
        const int rbase = row0 + wr + m * 16 + (lane >> 4) * 4;
#pragma unroll
        for (int n = 0; n < 4; ++n) {
            const int col = col0 + wc + n * 16 + fr;
#pragma unroll
            for (int r = 0; r < 4; ++r) {
                const int row = rbase + r;
                C[(size_t)row * NDIM + col] = (row <= col) ? acc[m][n][r] : 0.f;
            }
        }
    }
}

extern "C" void kernel_launch(void* const* d_in, const int* in_sizes, int n_in,
                              void* d_out, int out_size, void* d_ws,
                              size_t ws_size, hipStream_t stream) {
    const float* A = (const float*)d_in[0];
    const float* B = (const float*)d_in[1];
    float* C = (float*)d_out;
    trimm_mfma_kernel<<<dim3(NTOT), dim3(256), 0, stream>>>(A, B, C);
}

// Round 5
// 122.718 us; speedup vs baseline: 7.5859x; 1.1306x over previous
//
#include <hip/hip_runtime.h>
#include <hip/hip_bf16.h>

// C = triu( triu(A) @ triu(B) ), N=4096, fp32 in/out.
// bf16 MFMA (16x16x32); fp32->bf16 via packed RNE cvt during staging.
// Block (bi,bj) k-range = [bi*BM, (bj+1)*BN). Lower-tri blocks zero-fill.
// Reg double-buffer (T14): global loads for tile t+1 issue before tile t's
// MFMAs -> VMEM latency hides under compute instead of serializing.

#define NDIM 4096
#define BM 128
#define BN 128
#define BK 32
#define NBLK (NDIM / BM)                  // 32
#define NUPPER ((NBLK * (NBLK + 1)) / 2)  // 528
#define NTOT (NBLK * NBLK)                // 1024
#define LSTR 80                           // LDS row stride (64B data + 16B pad)

typedef __attribute__((ext_vector_type(8))) short short8;
typedef __attribute__((ext_vector_type(4))) float floatx4;

__device__ __forceinline__ int loff(int row, int kb) {
    return row * LSTR + kb;
}

// packed fp32x2 -> bf16x2 (RNE) -- compiler emits v_cvt_pk_bf16_f32
__device__ __forceinline__ unsigned pkbf(float a, float b) {
    __hip_bfloat162 h = __float22bfloat162_rn(make_float2(a, b));
    unsigned r;
    __builtin_memcpy(&r, &h, sizeof(r));
    return r;
}

__global__ __launch_bounds__(256) void trimm_mfma_kernel(
    const float* __restrict__ A, const float* __restrict__ B,
    float* __restrict__ C) {
    const int tid = threadIdx.x;
    const int id = blockIdx.x;
    int bi, bj;

    if (id >= NUPPER) {
        // ---- lower-triangle block: zero-fill (d_out is poisoned) ----
        int r = id - NUPPER;
        int p = 1;
        while (r >= p) { r -= p; ++p; }
        bi = p;
        bj = r;
        const size_t base = (size_t)bi * BM * NDIM + (size_t)bj * BN;
        const float4 z = make_float4(0.f, 0.f, 0.f, 0.f);
#pragma unroll
        for (int t = 0; t < 16; ++t) {
            const int f = tid + 256 * t;
            const int rr = f >> 5;
            const int cc = (f & 31) * 4;
            *reinterpret_cast<float4*>(&C[base + (size_t)rr * NDIM + cc]) = z;
        }
        return;
    }

    {   // ---- decode upper-tri block, longest k-range first ----
        int r = id;
        int L = NBLK;
        while (r >= NBLK + 1 - L) { r -= NBLK + 1 - L; --L; }
        bi = r;
        bj = bi + L - 1;
    }

    const int row0 = bi * BM;
    const int col0 = bj * BN;

    __shared__ __align__(16) char lAs[BM * LSTR];  // 10 KB [row][k] bf16
    __shared__ __align__(16) char lBs[BN * LSTR];  // 10 KB [col][k] bf16 (B^T)

    floatx4 acc[4][4];
    const floatx4 fz = {0.f, 0.f, 0.f, 0.f};
#pragma unroll
    for (int m = 0; m < 4; ++m)
#pragma unroll
        for (int n = 0; n < 4; ++n) acc[m][n] = fz;

    const int wv = tid >> 6;
    const int wr = (wv >> 1) * 64;
    const int wc = (wv & 1) * 64;
    const int lane = tid & 63;
    const int fr = lane & 15;
    const int kb = (lane >> 4) * 16;

    // A staging geometry: thread owns 4 float4 chunks (row ar[j], float kq aq[j])
    int ar[4], aq[4];
#pragma unroll
    for (int j = 0; j < 4; ++j) {
        const int f = tid + 256 * j;
        ar[j] = f >> 3;
        aq[j] = (f & 7) * 4;
    }
    // B staging geometry: thread owns column bn, k-half bkh
    const int bn = tid & 127;
    const int bkh = (tid >> 7) * 16;

    const int kend = col0 + BN;        // triu(B): k <= col
    const int kstart = row0;           // triu(A): k >= row

    float4 pa[4];
    float pb[16];

    // ---- prologue: prefetch first tile into registers ----
#pragma unroll
    for (int j = 0; j < 4; ++j)
        pa[j] = *reinterpret_cast<const float4*>(
            &A[(size_t)(row0 + ar[j]) * NDIM + kstart + aq[j]]);
#pragma unroll
    for (int kk = 0; kk < 16; ++kk)
        pb[kk] = B[(size_t)(kstart + bkh + kk) * NDIM + col0 + bn];

    for (int kt = kstart; kt < kend; kt += BK) {
        // ---- phase 1: convert + ds_write tile t from registers ----
#pragma unroll
        for (int j = 0; j < 4; ++j) {
            uint2 w;
            w.x = pkbf(pa[j].x, pa[j].y);
            w.y = pkbf(pa[j].z, pa[j].w);
            *reinterpret_cast<uint2*>(lAs + loff(ar[j], aq[j] * 2)) = w;
        }
        {
            uint4 w0, w1;
            w0.x = pkbf(pb[0], pb[1]);
            w0.y = pkbf(pb[2], pb[3]);
            w0.z = pkbf(pb[4], pb[5]);
            w0.w = pkbf(pb[6], pb[7]);
            w1.x = pkbf(pb[8], pb[9]);
            w1.y = pkbf(pb[10], pb[11]);
            w1.z = pkbf(pb[12], pb[13]);
            w1.w = pkbf(pb[14], pb[15]);
            *reinterpret_cast<uint4*>(lBs + loff(bn, bkh * 2)) = w0;
            *reinterpret_cast<uint4*>(lBs + loff(bn, bkh * 2 + 16)) = w1;
        }
        __syncthreads();

        // ---- phase 2: issue next tile's global loads (latency hides
        //      under the frag reads + MFMAs below) ----
        const int kn = kt + BK;
        if (kn < kend) {
#pragma unroll
            for (int j = 0; j < 4; ++j)
                pa[j] = *reinterpret_cast<const float4*>(
                    &A[(size_t)(row0 + ar[j]) * NDIM + kn + aq[j]]);
#pragma unroll
            for (int kk = 0; kk < 16; ++kk)
                pb[kk] = B[(size_t)(kn + bkh + kk) * NDIM + col0 + bn];
        }

        // ---- phase 3: fragments + 16 MFMAs ----
        short8 af[4], bf[4];
#pragma unroll
        for (int m = 0; m < 4; ++m)
            af[m] = *reinterpret_cast<const short8*>(
                lAs + loff(wr + m * 16 + fr, kb));
#pragma unroll
        for (int n = 0; n < 4; ++n)
            bf[n] = *reinterpret_cast<const short8*>(
                lBs + loff(wc + n * 16 + fr, kb));
#pragma unroll
        for (int m = 0; m < 4; ++m)
#pragma unroll
            for (int n = 0; n < 4; ++n)
                acc[m][n] = __builtin_amdgcn_mfma_f32_16x16x32_bf16(
                    af[m], bf[n], acc[m][n], 0, 0, 0);
        __syncthreads();
    }

    // ---- epilogue: C/D layout col=lane&15, row=(lane>>4)*4+reg ----
#pragma unroll
    for (int m = 0; m < 4; ++m) {
        const int rbase = row0 + wr + m * 16 + (lane >> 4) * 4;
#pragma unroll
        for (int n = 0; n < 4; ++n) {
            const int col = col0 + wc + n * 16 + fr;
#pragma unroll
            for (int r = 0; r < 4; ++r) {
                const int row = rbase + r;
                C[(size_t)row * NDIM + col] = (row <= col) ? acc[m][n][r] : 0.f;
            }
        }
    }
}

extern "C" void kernel_launch(void* const* d_in, const int* in_sizes, int n_in,
                              void* d_out, int out_size, void* d_ws,
                              size_t ws_size, hipStream_t stream) {
    const float* A = (const float*)d_in[0];
    const float* B = (const float*)d_in[1];
    float* C = (float*)d_out;
    trimm_mfma_kernel<<<dim3(NTOT), dim3(256), 0, stream>>>(A, B, C);
}